// Round 3
// baseline (119.878 us; speedup 1.0000x reference)
//
#include <hip/hip_runtime.h>
#include <hip/hip_bf16.h>

// Problem constants
#define N_IN   65536
#define N_OUTP 16384
#define KNB    16
#define FDIM   64
#define M_DIM  32          // N_DIST * N_PHI
#define KDIM   2048        // M_DIM * FDIM
#define OUT_D  256

typedef __bf16 bf16x8_t __attribute__((ext_vector_type(8)));
typedef float  f32x4_t  __attribute__((ext_vector_type(4)));

// ---------------------------------------------------------------------------
// pack_B: W_out (2048x256 f32, row-major) -> bf16 B-fragments for
// mfma_f32_16x16x32_bf16. Chunk c = (kk, nt, lane); lane l holds
// B[kk*32 + (l>>4)*8 + j][nt*16 + (l&15)], j = 0..7.
// ---------------------------------------------------------------------------
__global__ __launch_bounds__(256) void pack_B_kernel(
    const float* __restrict__ W, uint4* __restrict__ Bws)
{
  int c    = blockIdx.x * 256 + threadIdx.x;   // 65536 chunks
  int lane = c & 63;
  int nt   = (c >> 6) & 15;
  int kk   = c >> 10;
  int row0 = kk * 32 + (lane >> 4) * 8;
  int col  = nt * 16 + (lane & 15);
  union { unsigned short s[8]; uint4 v; } u;
#pragma unroll
  for (int j = 0; j < 8; ++j) {
    float f = W[(row0 + j) * OUT_D + col];
    __bf16 b = (__bf16)f;
    u.s[j] = __builtin_bit_cast(unsigned short, b);
  }
  Bws[c] = u.v;
}

// ---------------------------------------------------------------------------
// agg: weights + gather + normalize -> row-major bf16 A [N_OUTP][KDIM] in ws.
// ---------------------------------------------------------------------------
#define AGG_ROWS 8
__global__ __launch_bounds__(256) void agg_kernel(
    const float* __restrict__ x,
    const float* __restrict__ d_dists,
    const float* __restrict__ d_phi,
    const float* __restrict__ dists,
    const float* __restrict__ sigma_p,
    const float* __restrict__ kappa_p,
    const float* __restrict__ phi,
    const int*   __restrict__ nh_idx,
    unsigned*    __restrict__ Aws)     // row-major A, u32 = 2 packed bf16
{
  __shared__ float wbuf[AGG_ROWS * 16 * 32];
  __shared__ float winv[AGG_ROWS * 32];
  __shared__ int   idxb[AGG_ROWS * 16];

  const int t  = threadIdx.x;
  const int n0 = blockIdx.x * AGG_ROWS;

  const float sinv = 1.0f / sigma_p[0];
  const float kap  = kappa_p[0];
  float phiv[8], distv[4];
#pragma unroll
  for (int p = 0; p < 8; ++p) phiv[p] = phi[p];
#pragma unroll
  for (int d = 0; d < 4; ++d) distv[d] = dists[d];

  // weights: thread -> (r8 = (t>>1)>>4, k = (t>>1)&15, rep = t&1)
  {
    int rk = t >> 1, r8 = rk >> 4, k = rk & 15, rep = t & 1;
    int n = n0 + r8;
    float dd = d_dists[n * KNB + k];
    float dp = d_phi[n * KNB + k];
    float wp[8];
#pragma unroll
    for (int p = 0; p < 8; ++p) wp[p] = __expf(kap * __cosf(dp - phiv[p]));
#pragma unroll
    for (int dl = 0; dl < 2; ++dl) {
      int d = rep * 2 + dl;
      float td = (dd - distv[d]) * sinv;
      float wd = __expf(-0.5f * td * td);
      float4 w0 = make_float4(wd * wp[0], wd * wp[1], wd * wp[2], wd * wp[3]);
      float4 w1 = make_float4(wd * wp[4], wd * wp[5], wd * wp[6], wd * wp[7]);
      float* dst = wbuf + (r8 * 16 + k) * 32 + d * 8;
      *(float4*)(dst)     = w0;
      *(float4*)(dst + 4) = w1;
    }
    if (t < 128) {
      int r8b = t >> 4, kb = t & 15;
      idxb[r8b * 16 + kb] = nh_idx[(n0 + r8b) * KNB + kb];
    }
  }
  __syncthreads();

  // denominators: thread -> (r8 = t>>5, m = t&31)
  {
    int r8 = t >> 5, m = t & 31;
    float s = 0.f;
#pragma unroll
    for (int k = 0; k < 16; ++k) s += wbuf[(r8 * 16 + k) * 32 + m];
    winv[r8 * 32 + m] = 1.0f / (s + 1e-9f);
  }
  __syncthreads();

  // agg + store: thread -> (fg = t&31 [f-pair], r8 = t>>5)
  {
    int fg = t & 31, r8 = t >> 5;
    float acc0[32], acc1[32];
#pragma unroll
    for (int m = 0; m < 32; ++m) { acc0[m] = 0.f; acc1[m] = 0.f; }
    const float2* xp = (const float2*)x;
#pragma unroll
    for (int k = 0; k < 16; ++k) {
      int idx = idxb[r8 * 16 + k];
      float2 xv = xp[idx * 32 + fg];
      const float4* wrow4 = (const float4*)(wbuf + (r8 * 16 + k) * 32);
#pragma unroll
      for (int mm = 0; mm < 8; ++mm) {
        float4 wv = wrow4[mm];
        acc0[mm * 4 + 0] += wv.x * xv.x;  acc1[mm * 4 + 0] += wv.x * xv.y;
        acc0[mm * 4 + 1] += wv.y * xv.x;  acc1[mm * 4 + 1] += wv.y * xv.y;
        acc0[mm * 4 + 2] += wv.z * xv.x;  acc1[mm * 4 + 2] += wv.z * xv.y;
        acc0[mm * 4 + 3] += wv.w * xv.x;  acc1[mm * 4 + 3] += wv.w * xv.y;
      }
    }
    int row = n0 + r8;
    unsigned* dst = Aws + row * (KDIM / 2) + fg;  // u32 index = m*32 + fg
#pragma unroll
    for (int m = 0; m < 32; ++m) {
      float wn = winv[r8 * 32 + m];
      __bf16 b0 = (__bf16)(acc0[m] * wn);
      __bf16 b1 = (__bf16)(acc1[m] * wn);
      unsigned pk = ((unsigned)__builtin_bit_cast(unsigned short, b1) << 16)
                  |  (unsigned)__builtin_bit_cast(unsigned short, b0);
      dst[m * 32] = pk;
    }
  }
}

// ---------------------------------------------------------------------------
// gemm (split-K x4): out += A(16384x2048 bf16) @ B-frags over K-chunk of 512.
// Block = 32 rows x 256 cols x 512 K; 4 waves, each wave 32x64 cols
// (cacc[2][4]). Grid = 512 rb x 4 kc = 2048 blocks -> ~32 waves/CU.
// No LDS, no barriers; f32 atomic-fadd accumulation into zeroed out.
// ---------------------------------------------------------------------------
#define KC_SPLIT 4
#define KC_STEPS 16            // 16 x K32 = 512 per chunk
__global__ __launch_bounds__(256) void gemm_kernel(
    const char*  __restrict__ Aws,
    const uint4* __restrict__ Bws,
    float*       __restrict__ out)
{
  const int bx   = blockIdx.x;
  const int rb   = bx >> 2;          // row block: 32 rows
  const int kc   = bx & 3;           // K chunk
  const int t    = threadIdx.x;
  const int lane = t & 63;
  const int w    = t >> 6;

  f32x4_t cacc[2][4];
#pragma unroll
  for (int mt = 0; mt < 2; ++mt)
#pragma unroll
    for (int i = 0; i < 4; ++i)
      cacc[mt][i] = (f32x4_t){0.f, 0.f, 0.f, 0.f};

  // A: lane l reads 16B at row (l&15), k-byte (kk*32 + (l>>4)*8)*2
  const char* pa0 = Aws + (size_t)(rb * 32 + (lane & 15)) * (KDIM * 2)
                        + kc * (512 * 2) + (lane >> 4) * 16;
  const char* pa1 = pa0 + 16 * (KDIM * 2);
  // B chunks: idx = kkg*1024 + nt*64 + lane, nt = w*4 + i
  const uint4* pb = Bws + (size_t)(kc * KC_STEPS) * 1024 + w * 4 * 64 + lane;

  for (int kk = 0; kk < KC_STEPS; ++kk) {
    bf16x8_t a0 = __builtin_bit_cast(bf16x8_t, *(const uint4*)(pa0 + kk * 64));
    bf16x8_t a1 = __builtin_bit_cast(bf16x8_t, *(const uint4*)(pa1 + kk * 64));
#pragma unroll
    for (int i = 0; i < 4; ++i) {
      bf16x8_t b = __builtin_bit_cast(bf16x8_t, pb[kk * 1024 + i * 64]);
      cacc[0][i] = __builtin_amdgcn_mfma_f32_16x16x32_bf16(a0, b, cacc[0][i], 0, 0, 0);
      cacc[1][i] = __builtin_amdgcn_mfma_f32_16x16x32_bf16(a1, b, cacc[1][i], 0, 0, 0);
    }
  }

  // C/D layout: col = lane&15, row = (lane>>4)*4 + reg
#pragma unroll
  for (int mt = 0; mt < 2; ++mt)
#pragma unroll
    for (int i = 0; i < 4; ++i)
#pragma unroll
      for (int reg = 0; reg < 4; ++reg) {
        int row = rb * 32 + mt * 16 + (lane >> 4) * 4 + reg;
        int col = w * 64 + i * 16 + (lane & 15);
        __hip_atomic_fetch_add(&out[row * OUT_D + col], cacc[mt][i][reg],
                               __ATOMIC_RELAXED, __HIP_MEMORY_SCOPE_AGENT);
      }
}

// ===========================================================================
// Fallback (R1 fused kernel) — used only if ws_size is too small for A.
// ===========================================================================
#define TN 32
#define NBLK (N_OUTP / TN)
#define LDS_BYTES 148992
#define WBUF_OFF  131072
#define WINV_OFF  147456
#define IDX_OFF   148480

__global__ __launch_bounds__(256) void fused_kernel(
    const float* __restrict__ x,
    const float* __restrict__ d_dists,
    const float* __restrict__ d_phi,
    const float* __restrict__ dists,
    const float* __restrict__ sigma_p,
    const float* __restrict__ kappa_p,
    const float* __restrict__ phi,
    const uint4* __restrict__ Bws,
    const int*   __restrict__ nh_idx,
    float*       __restrict__ out)
{
  extern __shared__ char smem[];
  float* wbuf = (float*)(smem + WBUF_OFF);
  float* winv = (float*)(smem + WINV_OFF);
  int*   idxb = (int*)(smem + IDX_OFF);

  const int t  = threadIdx.x;
  const int n0 = blockIdx.x * TN;

  const float sinv = 1.0f / sigma_p[0];
  const float kap  = kappa_p[0];
  float phiv[8], distv[4];
#pragma unroll
  for (int p = 0; p < 8; ++p) phiv[p] = phi[p];
#pragma unroll
  for (int d = 0; d < 4; ++d) distv[d] = dists[d];

  for (int q = 0; q < 4; ++q) {
    const int rbase = q * 8;
    {
      int rk = t >> 1, r8 = rk >> 4, k = rk & 15, rep = t & 1;
      int n = n0 + rbase + r8;
      float dd = d_dists[n * KNB + k];
      float dp = d_phi[n * KNB + k];
      float wp[8];
#pragma unroll
      for (int p = 0; p < 8; ++p) wp[p] = __expf(kap * __cosf(dp - phiv[p]));
#pragma unroll
      for (int dl = 0; dl < 2; ++dl) {
        int d = rep * 2 + dl;
        float td = (dd - distv[d]) * sinv;
        float wd = __expf(-0.5f * td * td);
        float4 w0 = make_float4(wd * wp[0], wd * wp[1], wd * wp[2], wd * wp[3]);
        float4 w1 = make_float4(wd * wp[4], wd * wp[5], wd * wp[6], wd * wp[7]);
        float* dst = wbuf + (r8 * 16 + k) * 32 + d * 8;
        *(float4*)(dst)     = w0;
        *(float4*)(dst + 4) = w1;
      }
      if (t < 128) {
        int r8b = t >> 4, kb = t & 15;
        idxb[r8b * 16 + kb] = nh_idx[(n0 + rbase + r8b) * KNB + kb];
      }
    }
    __syncthreads();
    {
      int r8 = t >> 5, m = t & 31;
      float s = 0.f;
#pragma unroll
      for (int k = 0; k < 16; ++k) s += wbuf[(r8 * 16 + k) * 32 + m];
      winv[r8 * 32 + m] = 1.0f / (s + 1e-9f);
    }
    __syncthreads();
    {
      int fg = t & 31, r8 = t >> 5;
      float acc0[32], acc1[32];
#pragma unroll
      for (int m = 0; m < 32; ++m) { acc0[m] = 0.f; acc1[m] = 0.f; }
      const float2* xp = (const float2*)x;
      for (int k = 0; k < 16; ++k) {
        int idx = idxb[r8 * 16 + k];
        float2 xv = xp[idx * 32 + fg];
        const float4* wrow4 = (const float4*)(wbuf + (r8 * 16 + k) * 32);
#pragma unroll
        for (int mm = 0; mm < 8; ++mm) {
          float4 wv = wrow4[mm];
          acc0[mm * 4 + 0] += wv.x * xv.x;  acc1[mm * 4 + 0] += wv.x * xv.y;
          acc0[mm * 4 + 1] += wv.y * xv.x;  acc1[mm * 4 + 1] += wv.y * xv.y;
          acc0[mm * 4 + 2] += wv.z * xv.x;  acc1[mm * 4 + 2] += wv.z * xv.y;
          acc0[mm * 4 + 3] += wv.w * xv.x;  acc1[mm * 4 + 3] += wv.w * xv.y;
        }
      }
      int rg  = rbase + r8;
      int mt  = rg >> 4;
      int r15 = rg & 15;
#pragma unroll
      for (int m = 0; m < 32; ++m) {
        float wn = winv[r8 * 32 + m];
        float v0 = acc0[m] * wn;
        float v1 = acc1[m] * wn;
        int kg = m * 64 + fg * 2;
        int byte = mt * 65536 + (kg >> 5) * 1024 + ((kg >> 3) & 3) * 256
                 + r15 * 16 + (kg & 7) * 2;
        __bf16 b0 = (__bf16)v0, b1 = (__bf16)v1;
        unsigned pk = ((unsigned)__builtin_bit_cast(unsigned short, b1) << 16)
                    |  (unsigned)__builtin_bit_cast(unsigned short, b0);
        *(unsigned*)(smem + byte) = pk;
      }
    }
    __syncthreads();
  }

  {
    const int lane = t & 63;
    const int wave = t >> 6;
    f32x4_t cacc[2][4];
#pragma unroll
    for (int mt = 0; mt < 2; ++mt)
#pragma unroll
      for (int i = 0; i < 4; ++i)
        cacc[mt][i] = (f32x4_t){0.f, 0.f, 0.f, 0.f};
    for (int kk = 0; kk < 64; ++kk) {
      bf16x8_t a0 = __builtin_bit_cast(bf16x8_t,
          *(const uint4*)(smem + kk * 1024 + lane * 16));
      bf16x8_t a1 = __builtin_bit_cast(bf16x8_t,
          *(const uint4*)(smem + 65536 + kk * 1024 + lane * 16));
#pragma unroll
      for (int i = 0; i < 4; ++i) {
        uint4 braw = Bws[(kk * 16 + wave * 4 + i) * 64 + lane];
        bf16x8_t b = __builtin_bit_cast(bf16x8_t, braw);
        cacc[0][i] = __builtin_amdgcn_mfma_f32_16x16x32_bf16(a0, b, cacc[0][i], 0, 0, 0);
        cacc[1][i] = __builtin_amdgcn_mfma_f32_16x16x32_bf16(a1, b, cacc[1][i], 0, 0, 0);
      }
    }
#pragma unroll
    for (int mt = 0; mt < 2; ++mt)
#pragma unroll
      for (int i = 0; i < 4; ++i)
#pragma unroll
        for (int reg = 0; reg < 4; ++reg) {
          int row = n0 + mt * 16 + (lane >> 4) * 4 + reg;
          int col = wave * 64 + i * 16 + (lane & 15);
          out[row * OUT_D + col] = cacc[mt][i][reg];
        }
  }
}

// ===========================================================================
extern "C" void kernel_launch(void* const* d_in, const int* in_sizes, int n_in,
                              void* d_out, int out_size, void* d_ws, size_t ws_size,
                              hipStream_t stream) {
  const float* x      = (const float*)d_in[0];
  const float* dd     = (const float*)d_in[1];
  const float* dp     = (const float*)d_in[2];
  const float* dists  = (const float*)d_in[3];
  const float* sigma  = (const float*)d_in[4];
  const float* kappa  = (const float*)d_in[5];
  const float* phi    = (const float*)d_in[6];
  const float* W      = (const float*)d_in[7];
  const int*   nh     = (const int*)d_in[8];
  float*       out    = (float*)d_out;

  uint4* Bws = (uint4*)d_ws;                      // 1 MB of B-fragments
  char*  Aws = (char*)d_ws + (1 << 20);           // 64 MB row-major bf16 A

  const size_t need = (1u << 20) + (size_t)N_OUTP * KDIM * 2;  // 65 MB

  pack_B_kernel<<<256, 256, 0, stream>>>(W, Bws);

  if (ws_size >= need) {
    hipMemsetAsync(out, 0, (size_t)N_OUTP * OUT_D * sizeof(float), stream);
    agg_kernel<<<N_OUTP / AGG_ROWS, 256, 0, stream>>>(
        x, dd, dp, dists, sigma, kappa, phi, nh, (unsigned*)Aws);
    gemm_kernel<<<(N_OUTP / 32) * KC_SPLIT, 256, 0, stream>>>(Aws, Bws, out);
  } else {
    hipFuncSetAttribute((const void*)fused_kernel,
                        hipFuncAttributeMaxDynamicSharedMemorySize, LDS_BYTES);
    fused_kernel<<<NBLK, 256, LDS_BYTES, stream>>>(
        x, dd, dp, dists, sigma, kappa, phi, Bws, nh, out);
  }
}

// Round 4
// 71.966 us; speedup vs baseline: 1.6658x; 1.6658x over previous
//
#include <hip/hip_runtime.h>
#include <hip/hip_bf16.h>

// Problem constants
#define N_IN   65536
#define N_OUTP 16384
#define KNB    16
#define FDIM   64
#define M_DIM  32          // N_DIST * N_PHI
#define KDIM   2048        // M_DIM * FDIM
#define OUT_D  256

typedef __bf16 bf16x8_t __attribute__((ext_vector_type(8)));
typedef float  f32x4_t  __attribute__((ext_vector_type(4)));

// ---------------------------------------------------------------------------
// A storage ("stream" layout): per 16-row tile T (=row>>4), per K32-chunk kk,
// 64 lanes x 16B. Lane l holds rows (l&15), kg in [kk*32+(l>>4)*8, +8).
// u128 index = T*4096 + kk*64 + l.  Total 1024 tiles * 64KB = 64 MB.
// This makes BOTH the agg stores and the gemm A-loads contiguous per wave.
// ---------------------------------------------------------------------------

// ---------------------------------------------------------------------------
// pack_B: W_out (2048x256 f32) -> bf16 B-fragments. Chunk c = (kk, nt, lane);
// lane l holds B[kk*32 + (l>>4)*8 + j][nt*16 + (l&15)], j = 0..7.
// ---------------------------------------------------------------------------
__global__ __launch_bounds__(256) void pack_B_kernel(
    const float* __restrict__ W, uint4* __restrict__ Bws)
{
  int c    = blockIdx.x * 256 + threadIdx.x;   // 65536 chunks
  int lane = c & 63;
  int nt   = (c >> 6) & 15;
  int kk   = c >> 10;
  int row0 = kk * 32 + (lane >> 4) * 8;
  int col  = nt * 16 + (lane & 15);
  union { unsigned short s[8]; uint4 v; } u;
#pragma unroll
  for (int j = 0; j < 8; ++j) {
    float f = W[(row0 + j) * OUT_D + col];
    __bf16 b = (__bf16)f;
    u.s[j] = __builtin_bit_cast(unsigned short, b);
  }
  Bws[c] = u.v;
}

// ---------------------------------------------------------------------------
// agg: weights + gather + normalize -> A in fragment-stream layout (ws).
// 8 rows per block, 2048 blocks, 256 threads. Final store goes through an
// LDS transpose (pkbuf) so global writes are 128B-contiguous per half-wave.
// ---------------------------------------------------------------------------
#define AGG_ROWS 8
__global__ __launch_bounds__(256) void agg_kernel(
    const float* __restrict__ x,
    const float* __restrict__ d_dists,
    const float* __restrict__ d_phi,
    const float* __restrict__ dists,
    const float* __restrict__ sigma_p,
    const float* __restrict__ kappa_p,
    const float* __restrict__ phi,
    const int*   __restrict__ nh_idx,
    unsigned*    __restrict__ Aws)     // stream layout, u32 = 2 packed bf16
{
  __shared__ float    wbuf[AGG_ROWS * 16 * 32];
  __shared__ float    winv[AGG_ROWS * 32];
  __shared__ int      idxb[AGG_ROWS * 16];
  __shared__ unsigned pkbuf[AGG_ROWS * 1028];   // stride 1028 -> conflict-free

  const int t  = threadIdx.x;
  const int n0 = blockIdx.x * AGG_ROWS;
  const int T  = blockIdx.x >> 1;          // 16-row tile index
  const int r0 = (blockIdx.x & 1) * 8;     // row offset within tile

  const float sinv = 1.0f / sigma_p[0];
  const float kap  = kappa_p[0];
  float phiv[8], distv[4];
#pragma unroll
  for (int p = 0; p < 8; ++p) phiv[p] = phi[p];
#pragma unroll
  for (int d = 0; d < 4; ++d) distv[d] = dists[d];

  // weights: thread -> (r8 = (t>>1)>>4, k = (t>>1)&15, rep = t&1)
  {
    int rk = t >> 1, r8 = rk >> 4, k = rk & 15, rep = t & 1;
    int n = n0 + r8;
    float dd = d_dists[n * KNB + k];
    float dp = d_phi[n * KNB + k];
    float wp[8];
#pragma unroll
    for (int p = 0; p < 8; ++p) wp[p] = __expf(kap * __cosf(dp - phiv[p]));
#pragma unroll
    for (int dl = 0; dl < 2; ++dl) {
      int d = rep * 2 + dl;
      float td = (dd - distv[d]) * sinv;
      float wd = __expf(-0.5f * td * td);
      float4 w0 = make_float4(wd * wp[0], wd * wp[1], wd * wp[2], wd * wp[3]);
      float4 w1 = make_float4(wd * wp[4], wd * wp[5], wd * wp[6], wd * wp[7]);
      float* dst = wbuf + (r8 * 16 + k) * 32 + d * 8;
      *(float4*)(dst)     = w0;
      *(float4*)(dst + 4) = w1;
    }
    if (t < 128) {
      int r8b = t >> 4, kb = t & 15;
      idxb[r8b * 16 + kb] = nh_idx[(n0 + r8b) * KNB + kb];
    }
  }
  __syncthreads();

  // denominators: thread -> (r8 = t>>5, m = t&31)
  {
    int r8 = t >> 5, m = t & 31;
    float s = 0.f;
#pragma unroll
    for (int k = 0; k < 16; ++k) s += wbuf[(r8 * 16 + k) * 32 + m];
    winv[r8 * 32 + m] = 1.0f / (s + 1e-9f);
  }
  __syncthreads();

  // agg: thread -> (fg = t&31 [f-pair], r8 = t>>5); pk -> LDS transpose
  {
    int fg = t & 31, r8 = t >> 5;
    float acc0[32], acc1[32];
#pragma unroll
    for (int m = 0; m < 32; ++m) { acc0[m] = 0.f; acc1[m] = 0.f; }
    const float2* xp = (const float2*)x;
#pragma unroll
    for (int k = 0; k < 16; ++k) {
      int idx = idxb[r8 * 16 + k];
      float2 xv = xp[idx * 32 + fg];
      const float4* wrow4 = (const float4*)(wbuf + (r8 * 16 + k) * 32);
#pragma unroll
      for (int mm = 0; mm < 8; ++mm) {
        float4 wv = wrow4[mm];
        acc0[mm * 4 + 0] += wv.x * xv.x;  acc1[mm * 4 + 0] += wv.x * xv.y;
        acc0[mm * 4 + 1] += wv.y * xv.x;  acc1[mm * 4 + 1] += wv.y * xv.y;
        acc0[mm * 4 + 2] += wv.z * xv.x;  acc1[mm * 4 + 2] += wv.z * xv.y;
        acc0[mm * 4 + 3] += wv.w * xv.x;  acc1[mm * 4 + 3] += wv.w * xv.y;
      }
    }
    // pkbuf[r8][kidx = m*32+fg] ; u32 kidx covers kg = 2*kidx, 2*kidx+1
#pragma unroll
    for (int m = 0; m < 32; ++m) {
      float wn = winv[r8 * 32 + m];
      __bf16 b0 = (__bf16)(acc0[m] * wn);
      __bf16 b1 = (__bf16)(acc1[m] * wn);
      unsigned pk = ((unsigned)__builtin_bit_cast(unsigned short, b1) << 16)
                  |  (unsigned)__builtin_bit_cast(unsigned short, b0);
      pkbuf[r8 * 1028 + m * 32 + fg] = pk;
    }
  }
  __syncthreads();

  // coalesced copy-out to stream layout:
  // global u32 idx = T*16384 + kk*256 + ks*64 + (r0+rr)*4 + b
  //   where the u32 at (kk,ks,b) holds kidx = kk*16 + ks*4 + b.
  {
    int b   = t & 3;
    int rr  = (t >> 2) & 7;
    int ks  = (t >> 5) & 3;
    int kks = t >> 7;                      // 0 or 1
    unsigned* g = Aws + (size_t)T * 16384 + ks * 64 + (r0 + rr) * 4 + b;
    const unsigned* src = pkbuf + rr * 1028 + ks * 4 + b;
#pragma unroll
    for (int i = 0; i < 32; ++i) {
      int kk = kks * 32 + i;
      g[kk * 256] = src[kk * 16];
    }
  }
}

// ---------------------------------------------------------------------------
// gemm: out(16384x256) = A(stream) @ B(frags). 256 blocks x 512 threads.
// Block = 64 rows x 256 cols; wave w: rows (w&1)*32, cols (w>>1)*64.
// No LDS, no barriers, no atomics. Depth-2 register double-buffer.
// All loads are lane-contiguous (1KB per instruction).
// ---------------------------------------------------------------------------
__global__ __launch_bounds__(512) void gemm_kernel(
    const uint4* __restrict__ Astream,
    const uint4* __restrict__ Bws,
    float*       __restrict__ out)
{
  const int t    = threadIdx.x;
  const int lane = t & 63;
  const int w    = t >> 6;
  const int rb   = blockIdx.x;

  const uint4* pa = Astream + (size_t)(rb * 4 + (w & 1) * 2) * 4096 + lane;
  const uint4* pb = Bws + ((w >> 1) * 4) * 64 + lane;

  f32x4_t cacc[2][4];
#pragma unroll
  for (int mt = 0; mt < 2; ++mt)
#pragma unroll
    for (int i = 0; i < 4; ++i)
      cacc[mt][i] = (f32x4_t){0.f, 0.f, 0.f, 0.f};

  uint4 a[2][2], b[2][4];
#pragma unroll
  for (int s = 0; s < 2; ++s) {
    a[s][0] = pa[s * 64];
    a[s][1] = pa[4096 + s * 64];
#pragma unroll
    for (int i = 0; i < 4; ++i) b[s][i] = pb[s * 1024 + i * 64];
  }

#pragma unroll 4
  for (int kk = 0; kk < 64; ++kk) {
    const int s = kk & 1;
    bf16x8_t A0 = __builtin_bit_cast(bf16x8_t, a[s][0]);
    bf16x8_t A1 = __builtin_bit_cast(bf16x8_t, a[s][1]);
#pragma unroll
    for (int i = 0; i < 4; ++i) {
      bf16x8_t B = __builtin_bit_cast(bf16x8_t, b[s][i]);
      cacc[0][i] = __builtin_amdgcn_mfma_f32_16x16x32_bf16(A0, B, cacc[0][i], 0, 0, 0);
      cacc[1][i] = __builtin_amdgcn_mfma_f32_16x16x32_bf16(A1, B, cacc[1][i], 0, 0, 0);
    }
    if (kk < 62) {
      a[s][0] = pa[(kk + 2) * 64];
      a[s][1] = pa[4096 + (kk + 2) * 64];
#pragma unroll
      for (int i = 0; i < 4; ++i) b[s][i] = pb[(kk + 2) * 1024 + i * 64];
    }
  }

  // C/D layout: col = lane&15, row = (lane>>4)*4 + reg
  const int rbase = rb * 64 + (w & 1) * 32 + (lane >> 4) * 4;
  const int cbase = (w >> 1) * 64 + (lane & 15);
#pragma unroll
  for (int mt = 0; mt < 2; ++mt)
#pragma unroll
    for (int i = 0; i < 4; ++i)
#pragma unroll
      for (int reg = 0; reg < 4; ++reg)
        out[(rbase + mt * 16 + reg) * OUT_D + cbase + i * 16] = cacc[mt][i][reg];
}

// ===========================================================================
extern "C" void kernel_launch(void* const* d_in, const int* in_sizes, int n_in,
                              void* d_out, int out_size, void* d_ws, size_t ws_size,
                              hipStream_t stream) {
  const float* x      = (const float*)d_in[0];
  const float* dd     = (const float*)d_in[1];
  const float* dp     = (const float*)d_in[2];
  const float* dists  = (const float*)d_in[3];
  const float* sigma  = (const float*)d_in[4];
  const float* kappa  = (const float*)d_in[5];
  const float* phi    = (const float*)d_in[6];
  const float* W      = (const float*)d_in[7];
  const int*   nh     = (const int*)d_in[8];
  float*       out    = (float*)d_out;

  uint4* Bws = (uint4*)d_ws;                       // 1 MB of B-fragments
  uint4* Aws = (uint4*)((char*)d_ws + (1 << 20));  // 64 MB A, stream layout

  pack_B_kernel<<<256, 256, 0, stream>>>(W, Bws);
  agg_kernel<<<N_OUTP / AGG_ROWS, 256, 0, stream>>>(
      x, dd, dp, dists, sigma, kappa, phi, nh, (unsigned*)Aws);
  gemm_kernel<<<N_OUTP / 64, 512, 0, stream>>>(Aws, Bws, out);
}